// Round 8
// baseline (627.963 us; speedup 1.0000x reference)
//
#include <hip/hip_runtime.h>

#pragma clang fp contract(off)

#define NBOX 4096
#define MBOX 256
#define NBATCH 32
#define GEPS 1e-7f
#define GT 512          // greedy threads (8 waves)
#define GW 8
#define DEPTH 16        // init candidate-list depth
#define RDEPTH 8        // rebuild depth (zero-padded to DEPTH)

typedef unsigned long long u64;
typedef unsigned int u32;
typedef unsigned short u16;

// ---- greedy dynamic-LDS layout (bytes) ----
#define OFF_PRS   0        // float4[4096]      65536
#define OFF_TOP   65536    // u64[16][256]      32768 (entry-major)
#define OFF_G     98304    // float4[256]       4096
#define OFF_GAR   102400   // f32[256]          1024
#define OFF_CWL   103424   // u16[256]          512
#define OFF_CCNT  103936   // i32
#define OFF_REDA  103952   // f32[8]
#define OFF_REDB  103984   // f32[8]
#define OFF_REDC  104016   // f32[8]
#define LDS_BYTES 104064

__device__ __forceinline__ u64 shflxor_u64(u64 x, int m) {
  u32 lo = (u32)x, hi = (u32)(x >> 32);
  lo = __shfl_xor(lo, m, 64);
  hi = __shfl_xor(hi, m, 64);
  return ((u64)hi << 32) | (u64)lo;
}
__device__ __forceinline__ u64 shfl_u64(u64 x, int src) {
  u32 lo = (u32)x, hi = (u32)(x >> 32);
  lo = __shfl(lo, src, 64);
  hi = __shfl(hi, src, 64);
  return ((u64)hi << 32) | (u64)lo;
}

// exact IEEE, contract off -> bitwise identical everywhere it's computed
__device__ __forceinline__ u32 iou_bits(float4 a, float areaA, float4 g, float gar) {
  #pragma clang fp contract(off)
  float w = fminf(a.z, g.z) - fmaxf(a.x, g.x);
  float h = fminf(a.w, g.w) - fmaxf(a.y, g.y);
  w = fmaxf(w, 0.0f);
  h = fmaxf(h, 0.0f);
  float inter = w * h;
  float uni = (areaA + gar) - inter;
  float v = inter / uni;  // IoU >= 0: float bits order-preserving
  return __float_as_uint(v);
}

__device__ __forceinline__ float giou_loss(float ax1, float ay1, float ax2, float ay2,
                                           float bx1, float by1, float bx2, float by2) {
  #pragma clang fp contract(off)
  float xi1 = fmaxf(ax1, bx1), yi1 = fmaxf(ay1, by1);
  float xi2 = fminf(ax2, bx2), yi2 = fminf(ay2, by2);
  float inter = fmaxf(xi2 - xi1, 0.0f) * fmaxf(yi2 - yi1, 0.0f);
  float area1 = (ax2 - ax1) * (ay2 - ay1);
  float area2 = (bx2 - bx1) * (by2 - by1);
  float uni = (area1 + area2) - inter;
  float iou = inter / (uni + GEPS);
  float xc1 = fminf(ax1, bx1), yc1 = fminf(ay1, by1);
  float xc2 = fmaxf(ax2, bx2), yc2 = fmaxf(ay2, by2);
  float areac = (xc2 - xc1) * (yc2 - yc1);
  float giou = iou - (areac - uni) / (areac + GEPS);
  return 1.0f - giou;
}

// col-entry key: (iou<<13)|(4096-r)               -> max == (val desc, row asc)
// global key:    (iou<<22)|((4096-r)<<9)|(256-j)  -> max == (val desc, row asc, col asc)
//                == jnp.argmax flat-index tie-break, exactly.

// one wave per col: lane-local top-16 over 64 rows, then 16x wave-max extraction
__global__ __launch_bounds__(256) __attribute__((amdgpu_waves_per_eu(1, 4)))
void init_cols(const float4* __restrict__ pr, const float4* __restrict__ gt,
               u64* __restrict__ topG) {
  const int blk = blockIdx.x;
  const int b = blk >> 6, cg = blk & 63;
  const int tid = threadIdx.x, lane = tid & 63, wid = tid >> 6;
  const int j = cg * 4 + wid;
  const float4* prb = pr + (size_t)b * NBOX;
  float4 gb = gt[(size_t)b * MBOX + j];
  float gar = (gb.z - gb.x) * (gb.w - gb.y);
  u64 t[DEPTH];
  #pragma unroll
  for (int q = 0; q < DEPTH; ++q) t[q] = 0ull;
  for (int k = 0; k < 64; ++k) {
    int r = (k << 6) + lane;  // coalesced
    float4 a = prb[r];
    float areaA = (a.z - a.x) * (a.w - a.y);
    u64 key = ((u64)iou_bits(a, areaA, gb, gar) << 13) | (u64)(NBOX - r);
    if (key > t[DEPTH - 1]) {
      t[DEPTH - 1] = key;
      #pragma unroll
      for (int q = DEPTH - 1; q > 0; --q)
        if (t[q] > t[q - 1]) { u64 tmp = t[q]; t[q] = t[q - 1]; t[q - 1] = tmp; }
    }
  }
  u64* out = topG + ((size_t)b * MBOX + j) * DEPTH;
  int h = 0;
  for (int e = 0; e < DEPTH; ++e) {
    u64 cand = 0;
    #pragma unroll
    for (int q = 0; q < DEPTH; ++q) if (q == h) cand = t[q];  // static reg index
    u64 m = cand;
    #pragma unroll
    for (int o = 32; o; o >>= 1) {
      u64 q2 = shflxor_u64(m, o);
      if (q2 > m) m = q2;
    }
    if (cand == m && m) h++;  // keys distinct -> unique winner
    if (lane == 0) out[e] = m;
  }
}

// Exact sequential greedy, 256 steps, ZERO barriers on the common path:
// all 8 waves hold replicated register state (colbest 4/lane, pos, row-live
// bitmask 1 u64/lane) and redundantly compute the same step. Barriers only
// around rare list rebuilds (condition is uniform: identical data per wave).
__global__ __launch_bounds__(GT) __attribute__((amdgpu_waves_per_eu(1, 8)))
void greedy_kernel(const float4* __restrict__ pr, const float4* __restrict__ gt,
                   const u64* __restrict__ topG, float* __restrict__ partial) {
  extern __shared__ char smem[];
  float4* prs  = (float4*)(smem + OFF_PRS);
  u64* top     = (u64*)(smem + OFF_TOP);    // [e*256 + j]
  float4* g    = (float4*)(smem + OFF_G);
  float* garea = (float*)(smem + OFF_GAR);
  u16* cwl     = (u16*)(smem + OFF_CWL);
  int* ccnt    = (int*)(smem + OFF_CCNT);
  float* redA  = (float*)(smem + OFF_REDA);
  float* redB  = (float*)(smem + OFF_REDB);
  float* redC  = (float*)(smem + OFF_REDC);

  const int b = blockIdx.x, tid = threadIdx.x;
  const int lane = tid & 63, wid = tid >> 6;
  const float4* prb = pr + (size_t)b * NBOX;

  // ---- stage prs + negdiff; gt; candidate lists ----
  float negdiff = 0.0f, possum = 0.0f, negsub = 0.0f;
  #pragma unroll
  for (int k = 0; k < 8; ++k) {
    int r = tid + k * GT;
    float4 a = prb[r];
    prs[r] = a;
    negdiff += giou_loss(a.x, a.y, a.z, a.w, 0.0f, 0.0f, 0.0f, 0.0f);
  }
  if (tid < MBOX) {
    float4 gg = gt[(size_t)b * MBOX + tid];
    g[tid] = gg;
    garea[tid] = (gg.z - gg.x) * (gg.w - gg.y);
  }
  if (tid == 0) *ccnt = 0;
  #pragma unroll
  for (int k = 0; k < 8; ++k) {
    int idx = tid + k * GT;  // 4096 entries, coalesced; global layout [col][e]
    u64 e = topG[(size_t)b * (MBOX * DEPTH) + idx];
    top[(idx & (DEPTH - 1)) * MBOX + (idx >> 4)] = e;
  }
  __syncthreads();

  // ---- replicated per-wave register state ----
  u64 rowlive = ~0ull;        // bit k of lane l = row k*64+l live
  u64 cb[4];                  // colbest (global key) for cols lane*4+q
  u32 posreg = 0x01010101u;   // 4x 8-bit list positions (next index), init 1
  #pragma unroll
  for (int q = 0; q < 4; ++q) {
    int j = lane * 4 + q;
    u64 e0 = top[j];          // entry 0; all rows live; nonzero by construction
    cb[q] = ((e0 >> 13) << 22) | ((e0 & 0x1FFFull) << 9) | (u64)(MBOX - j);
  }

  // ---- 256 greedy steps ----
  for (int step = 0; step < MBOX; ++step) {
    // argmax over 256 colbests: 2-level local max + 6-level xor-reduce (no LDS)
    u64 m0 = cb[0] > cb[1] ? cb[0] : cb[1];
    u64 m1 = cb[2] > cb[3] ? cb[2] : cb[3];
    u64 m = m0 > m1 ? m0 : m1;
    #pragma unroll
    for (int o = 32; o; o >>= 1) {
      u64 q2 = shflxor_u64(m, o);
      if (q2 > m) m = q2;
    }
    const int i  = NBOX - (int)((m >> 9) & 0x1FFFull);
    const int jm = MBOX - (int)(m & 0x1FFull);
    // loss: rotate accumulation across waves to balance drift
    if (wid == (step & 7) && lane == (jm >> 2)) {
      float4 a = prs[i];
      float4 gg = g[jm];
      possum += giou_loss(a.x, a.y, a.z, a.w, gg.x, gg.y, gg.z, gg.w);
      negsub += giou_loss(a.x, a.y, a.z, a.w, 0.0f, 0.0f, 0.0f, 0.0f);
    }
    if (step == MBOX - 1) break;  // uniform
    // row i dies (every wave updates its own copy)
    if (lane == (i & 63)) rowlive &= ~(1ull << (i >> 6));
    // per-slot updates (statically unrolled; reg indices compile-time)
    u32 exmask = 0;
    #pragma unroll
    for (int q = 0; q < 4; ++q) {
      const int j = lane * 4 + q;
      u64 c = cb[q];
      if (j == jm) {
        cb[q] = 0ull;  // matched col retires
      } else if (c != 0ull && (NBOX - (int)((c >> 9) & 0x1FFFull)) == i) {
        // cached best row died: advance down the sorted list to first live entry
        int p = (int)((posreg >> (q * 8)) & 0xFFu);
        u64 ne = 0ull;
        while (p < DEPTH) {
          u64 e = top[p * MBOX + j];
          ++p;
          if (e == 0ull) { p = DEPTH; break; }  // zero-pad from shallow rebuild
          int r = NBOX - (int)(e & 0x1FFFull);
          u64 rl = shfl_u64(rowlive, r & 63);   // wave-private bpermute query
          if ((rl >> (r >> 6)) & 1ull) { ne = e; break; }
        }
        posreg = (posreg & ~(0xFFu << (q * 8))) | ((u32)p << (q * 8));
        if (ne) {
          cb[q] = ((ne >> 13) << 22) | ((ne & 0x1FFFull) << 9) | (u64)(MBOX - j);
        } else {
          cb[q] = 0ull;
          exmask |= (1u << q);  // exhausted -> rebuild before next argmax
        }
      }
    }
    // rare rebuild (uniform across waves: identical data -> identical exmask)
    u64 exball = __ballot(exmask != 0);
    if (exball != 0ull) {
      if (wid == 0 && exmask) {  // wave 0 publishes the worklist
        #pragma unroll
        for (int q = 0; q < 4; ++q)
          if (exmask & (1u << q)) {
            int x = atomicAdd(ccnt, 1);
            cwl[x] = (u16)(lane * 4 + q);
          }
      }
      __syncthreads();  // B1
      int cc = *ccnt;
      for (int x = wid; x < cc; x += GW) {  // split rebuilds across waves
        int jj = (int)cwl[x];
        float4 gb = g[jj];
        float gar = garea[jj];
        u64 t[RDEPTH];
        #pragma unroll
        for (int q = 0; q < RDEPTH; ++q) t[q] = 0ull;
        for (int k = 0; k < 64; ++k) {
          if ((rowlive >> k) & 1ull) {      // local liveness (transposed layout)
            int rr = (k << 6) + lane;
            float4 a = prs[rr];
            float areaA = (a.z - a.x) * (a.w - a.y);
            u64 key = ((u64)iou_bits(a, areaA, gb, gar) << 13) | (u64)(NBOX - rr);
            if (key > t[RDEPTH - 1]) {
              t[RDEPTH - 1] = key;
              #pragma unroll
              for (int q = RDEPTH - 1; q > 0; --q)
                if (t[q] > t[q - 1]) { u64 tmp = t[q]; t[q] = t[q - 1]; t[q - 1] = tmp; }
            }
          }
        }
        int h = 0;
        for (int e = 0; e < RDEPTH; ++e) {
          u64 cand = 0;
          #pragma unroll
          for (int q = 0; q < RDEPTH; ++q) if (q == h) cand = t[q];
          u64 mm = cand;
          #pragma unroll
          for (int o = 32; o; o >>= 1) {
            u64 q2 = shflxor_u64(mm, o);
            if (q2 > mm) mm = q2;
          }
          if (cand == mm && mm) h++;
          if (lane == 0) top[e * MBOX + jj] = mm;
        }
        if (lane == 0) {
          #pragma unroll
          for (int e = RDEPTH; e < DEPTH; ++e) top[e * MBOX + jj] = 0ull;
        }
      }
      __syncthreads();  // B2: rebuilt lists visible
      if (tid == 0) *ccnt = 0;  // safe: next reads are after next B1
      // owner lanes (every wave) reload rebuilt cols
      #pragma unroll
      for (int q = 0; q < 4; ++q) {
        if (exmask & (1u << q)) {
          int j = lane * 4 + q;
          u64 e0 = top[j];  // >=3840 live rows -> nonzero
          cb[q] = ((e0 >> 13) << 22) | ((e0 & 0x1FFFull) << 9) | (u64)(MBOX - j);
          posreg = (posreg & ~(0xFFu << (q * 8))) | (1u << (q * 8));
        }
      }
    }
  }

  // ---- final reduce: possum/256 + (negdiff - negsub)/3840 ----
  #pragma unroll
  for (int o = 32; o; o >>= 1) {
    possum  += __shfl_xor(possum, o, 64);
    negsub  += __shfl_xor(negsub, o, 64);
    negdiff += __shfl_xor(negdiff, o, 64);
  }
  if (lane == 0) { redA[wid] = possum; redB[wid] = negsub; redC[wid] = negdiff; }
  __syncthreads();
  if (tid == 0) {
    float pa = 0.0f, ns = 0.0f, ng = 0.0f;
    for (int w = 0; w < GW; ++w) { pa += redA[w]; ns += redB[w]; ng += redC[w]; }
    partial[b] = pa / 256.0f + (ng - ns) / 3840.0f;
  }
}

__global__ void finalize_kernel(const float* __restrict__ partial, float* __restrict__ out) {
  if (threadIdx.x == 0) {
    float s = 0.0f;
    for (int i = 0; i < NBATCH; ++i) s += partial[i];
    out[0] = s / 64.0f;  // /count(=32)/2
  }
}

extern "C" void kernel_launch(void* const* d_in, const int* in_sizes, int n_in,
                              void* d_out, int out_size, void* d_ws, size_t ws_size,
                              hipStream_t stream) {
  (void)in_sizes; (void)n_in; (void)out_size; (void)ws_size;
  const float4* pr = (const float4*)d_in[0];
  const float4* gt = (const float4*)d_in[1];
  char* ws = (char*)d_ws;
  u64* topG = (u64*)ws;                                    // 1 MB
  float* partial = (float*)(ws + (size_t)NBATCH * MBOX * DEPTH * 8);
  float* out = (float*)d_out;

  // allow >64KB dynamic LDS (idempotent host-side attribute; not a stream op)
  hipFuncSetAttribute((const void*)greedy_kernel,
                      hipFuncAttributeMaxDynamicSharedMemorySize, LDS_BYTES);

  hipLaunchKernelGGL(init_cols, dim3(NBATCH * 64), dim3(256), 0, stream, pr, gt, topG);
  hipLaunchKernelGGL(greedy_kernel, dim3(NBATCH), dim3(GT), LDS_BYTES, stream,
                     pr, gt, topG, partial);
  hipLaunchKernelGGL(finalize_kernel, dim3(1), dim3(64), 0, stream, partial, out);
}

// Round 9
// 366.167 us; speedup vs baseline: 1.7150x; 1.7150x over previous
//
#include <hip/hip_runtime.h>

#pragma clang fp contract(off)

#define NBOX 4096
#define MBOX 256
#define NBATCH 32
#define GEPS 1e-7f
#define DEPTH 16        // candidate-list depth (init)
#define RDEPTH 8        // rebuild depth (zero-padded to DEPTH)

typedef unsigned long long u64;
typedef unsigned int u32;
typedef unsigned short u16;

// ---- greedy dynamic-LDS layout (bytes) ----
#define OFF_PRS   0        // float4[4096]   65536
#define OFF_TOP   65536    // u64[256][16]   32768  ([j*16+e])
#define OFF_G     98304    // float4[256]    4096
#define OFF_GAR   102400   // f32[256]       1024
#define OFF_RL    103424   // u64[64]        512    (row-live mirror)
#define LDS_BYTES 103936

__device__ __forceinline__ u64 shflxor_u64(u64 x, int m) {
  u32 lo = (u32)x, hi = (u32)(x >> 32);
  lo = __shfl_xor(lo, m, 64);
  hi = __shfl_xor(hi, m, 64);
  return ((u64)hi << 32) | (u64)lo;
}

// exact IEEE, contract off -> bitwise identical everywhere it's computed
__device__ __forceinline__ u32 iou_bits(float4 a, float areaA, float4 g, float gar) {
  #pragma clang fp contract(off)
  float w = fminf(a.z, g.z) - fmaxf(a.x, g.x);
  float h = fminf(a.w, g.w) - fmaxf(a.y, g.y);
  w = fmaxf(w, 0.0f);
  h = fmaxf(h, 0.0f);
  float inter = w * h;
  float uni = (areaA + gar) - inter;
  float v = inter / uni;  // IoU >= 0: float bits order-preserving
  return __float_as_uint(v);
}

__device__ __forceinline__ float giou_loss(float ax1, float ay1, float ax2, float ay2,
                                           float bx1, float by1, float bx2, float by2) {
  #pragma clang fp contract(off)
  float xi1 = fmaxf(ax1, bx1), yi1 = fmaxf(ay1, by1);
  float xi2 = fminf(ax2, bx2), yi2 = fminf(ay2, by2);
  float inter = fmaxf(xi2 - xi1, 0.0f) * fmaxf(yi2 - yi1, 0.0f);
  float area1 = (ax2 - ax1) * (ay2 - ay1);
  float area2 = (bx2 - bx1) * (by2 - by1);
  float uni = (area1 + area2) - inter;
  float iou = inter / (uni + GEPS);
  float xc1 = fminf(ax1, bx1), yc1 = fminf(ay1, by1);
  float xc2 = fmaxf(ax2, bx2), yc2 = fmaxf(ay2, by2);
  float areac = (xc2 - xc1) * (yc2 - yc1);
  float giou = iou - (areac - uni) / (areac + GEPS);
  return 1.0f - giou;
}

// col-entry key: (iou<<13)|(4096-r)               -> max == (val desc, row asc)
// global key:    (iou<<22)|((4096-r)<<9)|(256-j)  -> max == (val desc, row asc, col asc)
//                == jnp.argmax flat-index tie-break, exactly.

// one wave per col: lane-local top-16 over 64 rows, then 16x wave-max extraction (R8-proven)
__global__ __launch_bounds__(256) __attribute__((amdgpu_waves_per_eu(1, 4)))
void init_cols(const float4* __restrict__ pr, const float4* __restrict__ gt,
               u64* __restrict__ topG) {
  const int blk = blockIdx.x;
  const int b = blk >> 6, cg = blk & 63;
  const int tid = threadIdx.x, lane = tid & 63, wid = tid >> 6;
  const int j = cg * 4 + wid;
  const float4* prb = pr + (size_t)b * NBOX;
  float4 gb = gt[(size_t)b * MBOX + j];
  float gar = (gb.z - gb.x) * (gb.w - gb.y);
  u64 t[DEPTH];
  #pragma unroll
  for (int q = 0; q < DEPTH; ++q) t[q] = 0ull;
  for (int k = 0; k < 64; ++k) {
    int r = (k << 6) + lane;  // coalesced
    float4 a = prb[r];
    float areaA = (a.z - a.x) * (a.w - a.y);
    u64 key = ((u64)iou_bits(a, areaA, gb, gar) << 13) | (u64)(NBOX - r);
    if (key > t[DEPTH - 1]) {
      t[DEPTH - 1] = key;
      #pragma unroll
      for (int q = DEPTH - 1; q > 0; --q)
        if (t[q] > t[q - 1]) { u64 tmp = t[q]; t[q] = t[q - 1]; t[q - 1] = tmp; }
    }
  }
  u64* out = topG + ((size_t)b * MBOX + j) * DEPTH;
  int h = 0;
  for (int e = 0; e < DEPTH; ++e) {
    u64 cand = 0;
    #pragma unroll
    for (int q = 0; q < DEPTH; ++q) if (q == h) cand = t[q];  // static reg index
    u64 m = cand;
    #pragma unroll
    for (int o = 32; o; o >>= 1) {
      u64 q2 = shflxor_u64(m, o);
      if (q2 > m) m = q2;
    }
    if (cand == m && m) h++;  // keys distinct -> unique winner
    if (lane == 0) out[e] = m;
  }
}

// Exact sequential greedy: ONE WAVE per batch. Zero barriers: everything is
// program-ordered within the wave (same-wave DS ops are ordered). State:
// colbest 4 cols/lane in regs; row-live bitmask in regs (transposed) + LDS
// mirror rl_lds[64] for the list-walk queries; candidate lists in LDS.
__global__ __launch_bounds__(64) __attribute__((amdgpu_waves_per_eu(1, 4)))
void greedy_kernel(const float4* __restrict__ pr, const float4* __restrict__ gt,
                   const u64* __restrict__ topG, float* __restrict__ partial) {
  extern __shared__ char smem[];
  float4* prs  = (float4*)(smem + OFF_PRS);
  u64* top     = (u64*)(smem + OFF_TOP);    // [j*DEPTH + e]
  float4* g    = (float4*)(smem + OFF_G);
  float* garea = (float*)(smem + OFF_GAR);
  u64* rl_lds  = (u64*)(smem + OFF_RL);

  const int b = blockIdx.x;
  const int lane = threadIdx.x;  // 64 threads = 1 wave
  const float4* prb = pr + (size_t)b * NBOX;

  // ---- stage prs + negdiff ----
  float negdiff = 0.0f, possum = 0.0f, negsub = 0.0f;
  for (int k = 0; k < 64; ++k) {
    int r = (k << 6) + lane;
    float4 a = prb[r];
    prs[r] = a;
    negdiff += giou_loss(a.x, a.y, a.z, a.w, 0.0f, 0.0f, 0.0f, 0.0f);
  }
  // ---- stage gt ----
  #pragma unroll
  for (int k = 0; k < 4; ++k) {
    int j = (k << 6) + lane;
    float4 gg = gt[(size_t)b * MBOX + j];
    g[j] = gg;
    garea[j] = (gg.z - gg.x) * (gg.w - gg.y);
  }
  // ---- stage candidate lists (32KB, float4 copies; layout matches [j][e]) ----
  {
    float4* dst = (float4*)top;
    const float4* src = (const float4*)(topG + (size_t)b * MBOX * DEPTH);
    for (int k = 0; k < 32; ++k) dst[(k << 6) + lane] = src[(k << 6) + lane];
  }
  // ---- register state ----
  u64 rowlive = ~0ull;          // bit k of lane l = row (k<<6)+l live
  rl_lds[lane] = rowlive;
  u64 cb[4];                    // colbest (global key) for col (q<<6)+lane
  u32 posreg = 0x01010101u;     // 4x 8-bit next-list-index
  #pragma unroll
  for (int q = 0; q < 4; ++q) {
    int j = (q << 6) + lane;
    u64 e0 = top[j * DEPTH];    // nonzero by construction
    cb[q] = ((e0 >> 13) << 22) | ((e0 & 0x1FFFull) << 9) | (u64)(MBOX - j);
  }

  // ---- 256 greedy steps, zero barriers ----
  for (int step = 0; step < MBOX; ++step) {
    // argmax over 256 colbests: 2-level reg max + 6-level xor-reduce
    u64 m0 = cb[0] > cb[1] ? cb[0] : cb[1];
    u64 m1 = cb[2] > cb[3] ? cb[2] : cb[3];
    u64 m = m0 > m1 ? m0 : m1;
    #pragma unroll
    for (int o = 32; o; o >>= 1) {
      u64 q2 = shflxor_u64(m, o);
      if (q2 > m) m = q2;
    }
    const int i  = NBOX - (int)((m >> 9) & 0x1FFFull);
    const int jm = MBOX - (int)(m & 0x1FFull);
    // loss on a rotating lane (off the dependence chain; compiler overlaps)
    if (lane == (step & 63)) {
      float4 a = prs[i];
      float4 gg = g[jm];
      possum += giou_loss(a.x, a.y, a.z, a.w, gg.x, gg.y, gg.z, gg.w);
      negsub += giou_loss(a.x, a.y, a.z, a.w, 0.0f, 0.0f, 0.0f, 0.0f);
    }
    if (step == MBOX - 1) break;
    // row i dies: owner lane updates reg + LDS mirror (same-wave DS order)
    if (lane == (i & 63)) {
      rowlive &= ~(1ull << (i >> 6));
      rl_lds[lane] = rowlive;
    }
    // slot updates
    u32 exmask = 0;
    #pragma unroll
    for (int q = 0; q < 4; ++q) {
      const int j = (q << 6) + lane;
      u64 c = cb[q];
      if (j == jm) {
        cb[q] = 0ull;  // matched col retires
      } else if (c != 0ull && (NBOX - (int)((c >> 9) & 0x1FFFull)) == i) {
        // cached best row died: advance down sorted list to first live entry
        int p = (int)((posreg >> (q * 8)) & 0xFFu);
        u64 ne = 0ull;
        while (p < DEPTH) {
          u64 e = top[j * DEPTH + p];
          ++p;
          if (e == 0ull) { p = DEPTH; break; }  // zero-pad from shallow rebuild
          int r = NBOX - (int)(e & 0x1FFFull);
          u64 rl = rl_lds[r & 63];
          if ((rl >> (r >> 6)) & 1ull) { ne = e; break; }
        }
        posreg = (posreg & ~(0xFFu << (q * 8))) | ((u32)p << (q * 8));
        if (ne) {
          cb[q] = ((ne >> 13) << 22) | ((ne & 0x1FFFull) << 9) | (u64)(MBOX - j);
        } else {
          cb[q] = 0ull;
          exmask |= (1u << q);
        }
      }
    }
    // rare inline rebuilds (wave-uniform loop; all lanes active inside)
    u64 exb = __ballot(exmask != 0);
    while (exb != 0ull) {
      const int src = (int)__ffsll((unsigned long long)exb) - 1;
      const u32 em = (u32)__shfl((int)exmask, src, 64);
      const int q = __ffs(em) - 1;
      const int jj = (q << 6) + src;
      if (lane == src) exmask &= ~(1u << q);
      exb = __ballot(exmask != 0);
      float4 gb = g[jj];
      float gar = garea[jj];
      u64 t[RDEPTH];
      #pragma unroll
      for (int z = 0; z < RDEPTH; ++z) t[z] = 0ull;
      for (int k = 0; k < 64; ++k) {
        if ((rowlive >> k) & 1ull) {  // own-lane liveness (transposed layout)
          int rr = (k << 6) + lane;
          float4 a = prs[rr];
          float areaA = (a.z - a.x) * (a.w - a.y);
          u64 key = ((u64)iou_bits(a, areaA, gb, gar) << 13) | (u64)(NBOX - rr);
          if (key > t[RDEPTH - 1]) {
            t[RDEPTH - 1] = key;
            #pragma unroll
            for (int z = RDEPTH - 1; z > 0; --z)
              if (t[z] > t[z - 1]) { u64 tmp = t[z]; t[z] = t[z - 1]; t[z - 1] = tmp; }
          }
        }
      }
      int h = 0;
      for (int e = 0; e < RDEPTH; ++e) {
        u64 cand = 0;
        #pragma unroll
        for (int z = 0; z < RDEPTH; ++z) if (z == h) cand = t[z];
        u64 mm = cand;
        #pragma unroll
        for (int o = 32; o; o >>= 1) {
          u64 q2 = shflxor_u64(mm, o);
          if (q2 > mm) mm = q2;
        }
        if (cand == mm && mm) h++;
        if (lane == 0) top[jj * DEPTH + e] = mm;
      }
      if (lane >= RDEPTH && lane < DEPTH) top[jj * DEPTH + lane] = 0ull;  // zero-pad
      if (lane == src) {
        u64 e0 = top[jj * DEPTH];  // >=3840 live rows -> nonzero
        cb[q] = ((e0 >> 13) << 22) | ((e0 & 0x1FFFull) << 9) | (u64)(MBOX - jj);
        posreg = (posreg & ~(0xFFu << (q * 8))) | (1u << (q * 8));
      }
    }
  }

  // ---- final wave reduce: possum/256 + (negdiff - negsub)/3840 ----
  #pragma unroll
  for (int o = 32; o; o >>= 1) {
    possum  += __shfl_xor(possum, o, 64);
    negsub  += __shfl_xor(negsub, o, 64);
    negdiff += __shfl_xor(negdiff, o, 64);
  }
  if (lane == 0)
    partial[b] = possum / 256.0f + (negdiff - negsub) / 3840.0f;
}

__global__ void finalize_kernel(const float* __restrict__ partial, float* __restrict__ out) {
  if (threadIdx.x == 0) {
    float s = 0.0f;
    for (int i = 0; i < NBATCH; ++i) s += partial[i];
    out[0] = s / 64.0f;  // /count(=32)/2
  }
}

extern "C" void kernel_launch(void* const* d_in, const int* in_sizes, int n_in,
                              void* d_out, int out_size, void* d_ws, size_t ws_size,
                              hipStream_t stream) {
  (void)in_sizes; (void)n_in; (void)out_size; (void)ws_size;
  const float4* pr = (const float4*)d_in[0];
  const float4* gt = (const float4*)d_in[1];
  char* ws = (char*)d_ws;
  u64* topG = (u64*)ws;                                    // 32*256*16*8 = 1 MB
  float* partial = (float*)(ws + (size_t)NBATCH * MBOX * DEPTH * 8);
  float* out = (float*)d_out;

  // allow >64KB dynamic LDS (idempotent host-side attribute; not a stream op)
  hipFuncSetAttribute((const void*)greedy_kernel,
                      hipFuncAttributeMaxDynamicSharedMemorySize, LDS_BYTES);

  hipLaunchKernelGGL(init_cols, dim3(NBATCH * 64), dim3(256), 0, stream, pr, gt, topG);
  hipLaunchKernelGGL(greedy_kernel, dim3(NBATCH), dim3(64), LDS_BYTES, stream,
                     pr, gt, topG, partial);
  hipLaunchKernelGGL(finalize_kernel, dim3(1), dim3(64), 0, stream, partial, out);
}

// Round 10
// 330.984 us; speedup vs baseline: 1.8973x; 1.1063x over previous
//
#include <hip/hip_runtime.h>

#pragma clang fp contract(off)

#define NBOX 4096
#define MBOX 256
#define NBATCH 32
#define GEPS 1e-7f
#define DEPTH 16        // candidate-list depth (init)
#define RDEPTH 8        // rebuild depth (zero-padded to DEPTH)

typedef unsigned long long u64;
typedef unsigned int u32;
typedef unsigned short u16;

// ---- greedy dynamic-LDS layout (bytes) ----
#define OFF_PRS   0        // float4[4096]   65536
#define OFF_TOP   65536    // u64[256][16]   32768  ([j*16+e])
#define OFF_G     98304    // float4[256]    4096
#define OFF_GAR   102400   // f32[256]       1024
#define OFF_RL    103424   // u64[64]        512    (row-live mirror)
#define LDS_BYTES 103936

__device__ __forceinline__ u64 shflxor_u64(u64 x, int m) {
  u32 lo = (u32)x, hi = (u32)(x >> 32);
  lo = __shfl_xor(lo, m, 64);
  hi = __shfl_xor(hi, m, 64);
  return ((u64)hi << 32) | (u64)lo;
}

// 64-lane u64 max-reduce on the VALU (DPP), result uniform (readlane 63).
// Levels: xor1, xor2 (quad_perm), half-mirror(8), mirror(16), bcast15, bcast31.
// After bcast31 lane 63 holds the global max (rocPRIM reduction pattern).
__device__ __forceinline__ u64 wave_max_u64(u64 x) {
  u32 lo = (u32)x, hi = (u32)(x >> 32);
#define DPPL(CTRL)                                                              \
  {                                                                             \
    u32 slo = (u32)__builtin_amdgcn_update_dpp(0, (int)lo, CTRL, 0xf, 0xf, true); \
    u32 shi = (u32)__builtin_amdgcn_update_dpp(0, (int)hi, CTRL, 0xf, 0xf, true); \
    if (((((u64)shi) << 32) | slo) > ((((u64)hi) << 32) | lo)) { lo = slo; hi = shi; } \
  }
  DPPL(0xB1)   // quad_perm [1,0,3,2]  = xor1
  DPPL(0x4E)   // quad_perm [2,3,0,1]  = xor2
  DPPL(0x141)  // row_half_mirror      (combine 8)
  DPPL(0x140)  // row_mirror           (combine 16)
  DPPL(0x142)  // row_bcast15          (rows prefix-combine)
  DPPL(0x143)  // row_bcast31          (lane 63 = global)
#undef DPPL
  lo = (u32)__builtin_amdgcn_readlane((int)lo, 63);
  hi = (u32)__builtin_amdgcn_readlane((int)hi, 63);
  return (((u64)hi) << 32) | lo;
}

// exact IEEE, contract off -> bitwise identical everywhere it's computed
__device__ __forceinline__ u32 iou_bits(float4 a, float areaA, float4 g, float gar) {
  #pragma clang fp contract(off)
  float w = fminf(a.z, g.z) - fmaxf(a.x, g.x);
  float h = fminf(a.w, g.w) - fmaxf(a.y, g.y);
  w = fmaxf(w, 0.0f);
  h = fmaxf(h, 0.0f);
  float inter = w * h;
  float uni = (areaA + gar) - inter;
  float v = inter / uni;  // IoU >= 0: float bits order-preserving
  return __float_as_uint(v);
}

__device__ __forceinline__ float giou_loss(float ax1, float ay1, float ax2, float ay2,
                                           float bx1, float by1, float bx2, float by2) {
  #pragma clang fp contract(off)
  float xi1 = fmaxf(ax1, bx1), yi1 = fmaxf(ay1, by1);
  float xi2 = fminf(ax2, bx2), yi2 = fminf(ay2, by2);
  float inter = fmaxf(xi2 - xi1, 0.0f) * fmaxf(yi2 - yi1, 0.0f);
  float area1 = (ax2 - ax1) * (ay2 - ay1);
  float area2 = (bx2 - bx1) * (by2 - by1);
  float uni = (area1 + area2) - inter;
  float iou = inter / (uni + GEPS);
  float xc1 = fminf(ax1, bx1), yc1 = fminf(ay1, by1);
  float xc2 = fmaxf(ax2, bx2), yc2 = fmaxf(ay2, by2);
  float areac = (xc2 - xc1) * (yc2 - yc1);
  float giou = iou - (areac - uni) / (areac + GEPS);
  return 1.0f - giou;
}

// col-entry key: (iou<<13)|(4096-r)               -> max == (val desc, row asc)
// global key:    (iou<<22)|((4096-r)<<9)|(256-j)  -> max == (val desc, row asc, col asc)
//                == jnp.argmax flat-index tie-break, exactly.

// one wave per col: lane-local top-16 over 64 rows, then 16x DPP wave-max extraction
__global__ __launch_bounds__(256) __attribute__((amdgpu_waves_per_eu(1, 4)))
void init_cols(const float4* __restrict__ pr, const float4* __restrict__ gt,
               u64* __restrict__ topG) {
  const int blk = blockIdx.x;
  const int b = blk >> 6, cg = blk & 63;
  const int tid = threadIdx.x, lane = tid & 63, wid = tid >> 6;
  const int j = cg * 4 + wid;
  const float4* prb = pr + (size_t)b * NBOX;
  float4 gb = gt[(size_t)b * MBOX + j];
  float gar = (gb.z - gb.x) * (gb.w - gb.y);
  u64 t[DEPTH];
  #pragma unroll
  for (int q = 0; q < DEPTH; ++q) t[q] = 0ull;
  for (int k = 0; k < 64; ++k) {
    int r = (k << 6) + lane;  // coalesced
    float4 a = prb[r];
    float areaA = (a.z - a.x) * (a.w - a.y);
    u64 key = ((u64)iou_bits(a, areaA, gb, gar) << 13) | (u64)(NBOX - r);
    if (key > t[DEPTH - 1]) {
      t[DEPTH - 1] = key;
      #pragma unroll
      for (int q = DEPTH - 1; q > 0; --q)
        if (t[q] > t[q - 1]) { u64 tmp = t[q]; t[q] = t[q - 1]; t[q - 1] = tmp; }
    }
  }
  u64* out = topG + ((size_t)b * MBOX + j) * DEPTH;
  int h = 0;
  for (int e = 0; e < DEPTH; ++e) {
    u64 cand = 0;
    #pragma unroll
    for (int q = 0; q < DEPTH; ++q) if (q == h) cand = t[q];  // static reg index
    u64 m = wave_max_u64(cand);
    if (cand == m && m) h++;  // keys distinct -> unique winner
    if (lane == 0) out[e] = m;
  }
}

// Exact sequential greedy: ONE WAVE per batch, zero barriers, DPP argmax.
// State: colbest cb[4] + lookahead la[4] in regs (4 cols/lane); row-live
// bitmask in regs (transposed) + LDS mirror rl_lds[64]; candidate lists in LDS.
__global__ __launch_bounds__(64) __attribute__((amdgpu_waves_per_eu(1, 4)))
void greedy_kernel(const float4* __restrict__ pr, const float4* __restrict__ gt,
                   const u64* __restrict__ topG, float* __restrict__ partial) {
  extern __shared__ char smem[];
  float4* prs  = (float4*)(smem + OFF_PRS);
  u64* top     = (u64*)(smem + OFF_TOP);    // [j*DEPTH + e]
  float4* g    = (float4*)(smem + OFF_G);
  float* garea = (float*)(smem + OFF_GAR);
  u64* rl_lds  = (u64*)(smem + OFF_RL);

  const int b = blockIdx.x;
  const int lane = threadIdx.x;  // 64 threads = 1 wave
  const float4* prb = pr + (size_t)b * NBOX;

  // ---- stage prs + negdiff ----
  float negdiff = 0.0f, possum = 0.0f, negsub = 0.0f;
  for (int k = 0; k < 64; ++k) {
    int r = (k << 6) + lane;
    float4 a = prb[r];
    prs[r] = a;
    negdiff += giou_loss(a.x, a.y, a.z, a.w, 0.0f, 0.0f, 0.0f, 0.0f);
  }
  // ---- stage gt ----
  #pragma unroll
  for (int k = 0; k < 4; ++k) {
    int j = (k << 6) + lane;
    float4 gg = gt[(size_t)b * MBOX + j];
    g[j] = gg;
    garea[j] = (gg.z - gg.x) * (gg.w - gg.y);
  }
  // ---- stage candidate lists (32KB, float4 copies; layout matches [j][e]) ----
  {
    float4* dst = (float4*)top;
    const float4* src = (const float4*)(topG + (size_t)b * MBOX * DEPTH);
    for (int k = 0; k < 32; ++k) dst[(k << 6) + lane] = src[(k << 6) + lane];
  }
  // ---- register state ----
  u64 rowlive = ~0ull;          // bit k of lane l = row (k<<6)+l live
  rl_lds[lane] = rowlive;
  u64 cb[4];                    // colbest (global key) for col (q<<6)+lane
  u64 la[4];                    // lookahead: next raw list entry (0 = exhausted)
  u32 posreg = 0x02020202u;     // 4x 8-bit next-list-index (after la)
  #pragma unroll
  for (int q = 0; q < 4; ++q) {
    int j = (q << 6) + lane;
    u64 e0 = top[j * DEPTH];     // nonzero by construction
    u64 e1 = top[j * DEPTH + 1];
    cb[q] = ((e0 >> 13) << 22) | ((e0 & 0x1FFFull) << 9) | (u64)(MBOX - j);
    la[q] = e1;
  }

  // ---- 256 greedy steps, zero barriers, DPP argmax ----
  for (int step = 0; step < MBOX; ++step) {
    // argmax over 256 colbests: 2-level reg max + VALU DPP reduce (uniform out)
    u64 m0 = cb[0] > cb[1] ? cb[0] : cb[1];
    u64 m1 = cb[2] > cb[3] ? cb[2] : cb[3];
    u64 m = wave_max_u64(m0 > m1 ? m0 : m1);
    const int i  = NBOX - (int)((m >> 9) & 0x1FFFull);
    const int jm = MBOX - (int)(m & 0x1FFull);
    // loss on a rotating lane (off the dependence chain)
    if (lane == (step & 63)) {
      float4 a = prs[i];
      float4 gg = g[jm];
      possum += giou_loss(a.x, a.y, a.z, a.w, gg.x, gg.y, gg.z, gg.w);
      negsub += giou_loss(a.x, a.y, a.z, a.w, 0.0f, 0.0f, 0.0f, 0.0f);
    }
    if (step == MBOX - 1) break;
    // row i dies: owner lane updates reg + LDS mirror (same-wave DS order)
    if (lane == (i & 63)) {
      rowlive &= ~(1ull << (i >> 6));
      rl_lds[lane] = rowlive;
    }
    // slot updates: lookahead-first walk
    u32 exmask = 0;
    #pragma unroll
    for (int q = 0; q < 4; ++q) {
      const int j = (q << 6) + lane;
      u64 c = cb[q];
      if (j == jm) {
        cb[q] = 0ull;  // matched col retires
      } else if (c != 0ull && (NBOX - (int)((c >> 9) & 0x1FFFull)) == i) {
        int p = (int)((posreg >> (q * 8)) & 0xFFu);
        u64 e = la[q];  // pre-loaded candidate: one dependent rl read on the chain
        for (;;) {
          if (e == 0ull) break;  // exhausted (or zero-pad)
          int r = NBOX - (int)(e & 0x1FFFull);
          if ((rl_lds[r & 63] >> (r >> 6)) & 1ull) break;  // live
          e = (p < DEPTH) ? top[j * DEPTH + p] : 0ull;
          ++p;
        }
        if (e != 0ull) {
          cb[q] = ((e >> 13) << 22) | ((e & 0x1FFFull) << 9) | (u64)(MBOX - j);
          la[q] = (p < DEPTH) ? top[j * DEPTH + p] : 0ull;  // refill: latency hides
          ++p;
          posreg = (posreg & ~(0xFFu << (q * 8))) | ((u32)p << (q * 8));
        } else {
          cb[q] = 0ull;
          exmask |= (1u << q);
        }
      }
    }
    // rare inline rebuilds (wave-uniform loop; all lanes active inside)
    u64 exb = __ballot(exmask != 0);
    while (exb != 0ull) {
      const int src = (int)__ffsll((unsigned long long)exb) - 1;
      const u32 em = (u32)__shfl((int)exmask, src, 64);
      const int q = __ffs(em) - 1;
      const int jj = (q << 6) + src;
      if (lane == src) exmask &= ~(1u << q);
      exb = __ballot(exmask != 0);
      float4 gb = g[jj];
      float gar = garea[jj];
      u64 t[RDEPTH];
      #pragma unroll
      for (int z = 0; z < RDEPTH; ++z) t[z] = 0ull;
      for (int k = 0; k < 64; ++k) {
        if ((rowlive >> k) & 1ull) {  // own-lane liveness (transposed layout)
          int rr = (k << 6) + lane;
          float4 a = prs[rr];
          float areaA = (a.z - a.x) * (a.w - a.y);
          u64 key = ((u64)iou_bits(a, areaA, gb, gar) << 13) | (u64)(NBOX - rr);
          if (key > t[RDEPTH - 1]) {
            t[RDEPTH - 1] = key;
            #pragma unroll
            for (int z = RDEPTH - 1; z > 0; --z)
              if (t[z] > t[z - 1]) { u64 tmp = t[z]; t[z] = t[z - 1]; t[z - 1] = tmp; }
          }
        }
      }
      u64 ent0 = 0ull, ent1 = 0ull;
      int h = 0;
      for (int e = 0; e < RDEPTH; ++e) {
        u64 cand = 0;
        #pragma unroll
        for (int z = 0; z < RDEPTH; ++z) if (z == h) cand = t[z];
        u64 mm = wave_max_u64(cand);
        if (cand == mm && mm) h++;
        if (e == 0) ent0 = mm;
        if (e == 1) ent1 = mm;
        if (lane == 0) top[jj * DEPTH + e] = mm;
      }
      if (lane >= RDEPTH && lane < DEPTH) top[jj * DEPTH + lane] = 0ull;  // zero-pad
      if (lane == src) {
        cb[q] = ((ent0 >> 13) << 22) | ((ent0 & 0x1FFFull) << 9) | (u64)(MBOX - jj);
        la[q] = ent1;  // >=3840 live rows -> ent0/ent1 nonzero, live
        posreg = (posreg & ~(0xFFu << (q * 8))) | (2u << (q * 8));
      }
    }
  }

  // ---- final wave reduce: possum/256 + (negdiff - negsub)/3840 ----
  #pragma unroll
  for (int o = 32; o; o >>= 1) {
    possum  += __shfl_xor(possum, o, 64);
    negsub  += __shfl_xor(negsub, o, 64);
    negdiff += __shfl_xor(negdiff, o, 64);
  }
  if (lane == 0)
    partial[b] = possum / 256.0f + (negdiff - negsub) / 3840.0f;
}

__global__ void finalize_kernel(const float* __restrict__ partial, float* __restrict__ out) {
  if (threadIdx.x == 0) {
    float s = 0.0f;
    for (int i = 0; i < NBATCH; ++i) s += partial[i];
    out[0] = s / 64.0f;  // /count(=32)/2
  }
}

extern "C" void kernel_launch(void* const* d_in, const int* in_sizes, int n_in,
                              void* d_out, int out_size, void* d_ws, size_t ws_size,
                              hipStream_t stream) {
  (void)in_sizes; (void)n_in; (void)out_size; (void)ws_size;
  const float4* pr = (const float4*)d_in[0];
  const float4* gt = (const float4*)d_in[1];
  char* ws = (char*)d_ws;
  u64* topG = (u64*)ws;                                    // 32*256*16*8 = 1 MB
  float* partial = (float*)(ws + (size_t)NBATCH * MBOX * DEPTH * 8);
  float* out = (float*)d_out;

  // allow >64KB dynamic LDS (idempotent host-side attribute; not a stream op)
  hipFuncSetAttribute((const void*)greedy_kernel,
                      hipFuncAttributeMaxDynamicSharedMemorySize, LDS_BYTES);

  hipLaunchKernelGGL(init_cols, dim3(NBATCH * 64), dim3(256), 0, stream, pr, gt, topG);
  hipLaunchKernelGGL(greedy_kernel, dim3(NBATCH), dim3(64), LDS_BYTES, stream,
                     pr, gt, topG, partial);
  hipLaunchKernelGGL(finalize_kernel, dim3(1), dim3(64), 0, stream, partial, out);
}

// Round 11
// 223.009 us; speedup vs baseline: 2.8159x; 1.4842x over previous
//
#include <hip/hip_runtime.h>

#pragma clang fp contract(off)

#define NBOX 4096
#define MBOX 256
#define NBATCH 32
#define GEPS 1e-7f
#define DEPTH 12        // candidate-list depth (init)
#define RDEPTH 8        // rebuild depth (zero-padded to DEPTH)

typedef unsigned long long u64;
typedef unsigned int u32;
typedef unsigned short u16;

// ---- greedy dynamic-LDS layout (bytes) ----
#define OFF_PRS   0        // float4[4096]   65536
#define OFF_TOP   65536    // u64[256][12]   24576  ([j*12+e])
#define OFF_G     90112    // float4[256]    4096
#define OFF_GAR   94208    // f32[256]       1024
#define OFF_RL    95232    // u64[64]        512    (row-live mirror)
#define OFF_MATCH 95744    // u32[256]       1024   (packed rowfield<<9|colfield)
#define LDS_BYTES 96768

__device__ __forceinline__ u64 shflxor_u64(u64 x, int m) {
  u32 lo = (u32)x, hi = (u32)(x >> 32);
  lo = __shfl_xor(lo, m, 64);
  hi = __shfl_xor(hi, m, 64);
  return ((u64)hi << 32) | (u64)lo;
}

// 64-lane u64 max-reduce on the VALU (DPP), result uniform (readlane 63).
__device__ __forceinline__ u64 wave_max_u64(u64 x) {
  u32 lo = (u32)x, hi = (u32)(x >> 32);
#define DPPL(CTRL)                                                              \
  {                                                                             \
    u32 slo = (u32)__builtin_amdgcn_update_dpp(0, (int)lo, CTRL, 0xf, 0xf, true); \
    u32 shi = (u32)__builtin_amdgcn_update_dpp(0, (int)hi, CTRL, 0xf, 0xf, true); \
    if (((((u64)shi) << 32) | slo) > ((((u64)hi) << 32) | lo)) { lo = slo; hi = shi; } \
  }
  DPPL(0xB1)   // quad_perm xor1
  DPPL(0x4E)   // quad_perm xor2
  DPPL(0x141)  // row_half_mirror
  DPPL(0x140)  // row_mirror
  DPPL(0x142)  // row_bcast15
  DPPL(0x143)  // row_bcast31 -> lane 63 global
#undef DPPL
  lo = (u32)__builtin_amdgcn_readlane((int)lo, 63);
  hi = (u32)__builtin_amdgcn_readlane((int)hi, 63);
  return (((u64)hi) << 32) | lo;
}

// exact IEEE, contract off -> bitwise identical everywhere it's computed
__device__ __forceinline__ u32 iou_bits(float4 a, float areaA, float4 g, float gar) {
  #pragma clang fp contract(off)
  float w = fminf(a.z, g.z) - fmaxf(a.x, g.x);
  float h = fminf(a.w, g.w) - fmaxf(a.y, g.y);
  w = fmaxf(w, 0.0f);
  h = fmaxf(h, 0.0f);
  float inter = w * h;
  float uni = (areaA + gar) - inter;
  float v = inter / uni;  // IoU >= 0: float bits order-preserving
  return __float_as_uint(v);
}

__device__ __forceinline__ float giou_loss(float ax1, float ay1, float ax2, float ay2,
                                           float bx1, float by1, float bx2, float by2) {
  #pragma clang fp contract(off)
  float xi1 = fmaxf(ax1, bx1), yi1 = fmaxf(ay1, by1);
  float xi2 = fminf(ax2, bx2), yi2 = fminf(ay2, by2);
  float inter = fmaxf(xi2 - xi1, 0.0f) * fmaxf(yi2 - yi1, 0.0f);
  float area1 = (ax2 - ax1) * (ay2 - ay1);
  float area2 = (bx2 - bx1) * (by2 - by1);
  float uni = (area1 + area2) - inter;
  float iou = inter / (uni + GEPS);
  float xc1 = fminf(ax1, bx1), yc1 = fminf(ay1, by1);
  float xc2 = fmaxf(ax2, bx2), yc2 = fmaxf(ay2, by2);
  float areac = (xc2 - xc1) * (yc2 - yc1);
  float giou = iou - (areac - uni) / (areac + GEPS);
  return 1.0f - giou;
}

// col-entry key: (iou<<13)|(4096-r)               -> max == (val desc, row asc)
// global key:    (iou<<22)|((4096-r)<<9)|(256-j)  -> max == (val desc, row asc, col asc)
//                == jnp.argmax flat-index tie-break, exactly.

// one wave per col: lane-local top-12 over 64 rows, then 12x DPP wave-max extraction
__global__ __launch_bounds__(256) __attribute__((amdgpu_waves_per_eu(1, 4)))
void init_cols(const float4* __restrict__ pr, const float4* __restrict__ gt,
               u64* __restrict__ topG) {
  const int blk = blockIdx.x;
  const int b = blk >> 6, cg = blk & 63;
  const int tid = threadIdx.x, lane = tid & 63, wid = tid >> 6;
  const int j = cg * 4 + wid;
  const float4* prb = pr + (size_t)b * NBOX;
  float4 gb = gt[(size_t)b * MBOX + j];
  float gar = (gb.z - gb.x) * (gb.w - gb.y);
  u64 t[DEPTH];
  #pragma unroll
  for (int q = 0; q < DEPTH; ++q) t[q] = 0ull;
  for (int k = 0; k < 64; ++k) {
    int r = (k << 6) + lane;  // coalesced
    float4 a = prb[r];
    float areaA = (a.z - a.x) * (a.w - a.y);
    u64 key = ((u64)iou_bits(a, areaA, gb, gar) << 13) | (u64)(NBOX - r);
    if (key > t[DEPTH - 1]) {
      t[DEPTH - 1] = key;
      #pragma unroll
      for (int q = DEPTH - 1; q > 0; --q)
        if (t[q] > t[q - 1]) { u64 tmp = t[q]; t[q] = t[q - 1]; t[q - 1] = tmp; }
    }
  }
  u64* out = topG + ((size_t)b * MBOX + j) * DEPTH;
  int h = 0;
  for (int e = 0; e < DEPTH; ++e) {
    u64 cand = 0;
    #pragma unroll
    for (int q = 0; q < DEPTH; ++q) if (q == h) cand = t[q];  // static reg index
    u64 m = wave_max_u64(cand);
    if (cand == m && m) h++;  // keys distinct -> unique winner
    if (lane == 0) out[e] = m;
  }
}

// Exact sequential greedy: ONE WAVE per batch, zero barriers, DPP argmax,
// deferred loss. State: colbest cb[4] + lookahead la[4] in regs (4 cols/lane);
// row-live bitmask in regs (transposed) + LDS mirror; candidate lists in LDS.
__global__ __launch_bounds__(64) __attribute__((amdgpu_waves_per_eu(1, 4)))
void greedy_kernel(const float4* __restrict__ pr, const float4* __restrict__ gt,
                   const u64* __restrict__ topG, float* __restrict__ partial) {
  extern __shared__ char smem[];
  float4* prs  = (float4*)(smem + OFF_PRS);
  u64* top     = (u64*)(smem + OFF_TOP);    // [j*DEPTH + e]
  float4* g    = (float4*)(smem + OFF_G);
  float* garea = (float*)(smem + OFF_GAR);
  u64* rl_lds  = (u64*)(smem + OFF_RL);
  u32* match   = (u32*)(smem + OFF_MATCH);

  const int b = blockIdx.x;
  const int lane = threadIdx.x;  // 64 threads = 1 wave
  const float4* prb = pr + (size_t)b * NBOX;

  // ---- stage prs + negdiff ----
  float negdiff = 0.0f, possum = 0.0f, negsub = 0.0f;
  for (int k = 0; k < 64; ++k) {
    int r = (k << 6) + lane;
    float4 a = prb[r];
    prs[r] = a;
    negdiff += giou_loss(a.x, a.y, a.z, a.w, 0.0f, 0.0f, 0.0f, 0.0f);
  }
  // ---- stage gt ----
  #pragma unroll
  for (int k = 0; k < 4; ++k) {
    int j = (k << 6) + lane;
    float4 gg = gt[(size_t)b * MBOX + j];
    g[j] = gg;
    garea[j] = (gg.z - gg.x) * (gg.w - gg.y);
  }
  // ---- stage candidate lists (24KB, float4 copies; linear both sides) ----
  {
    float4* dst = (float4*)top;
    const float4* src = (const float4*)(topG + (size_t)b * MBOX * DEPTH);
    for (int k = 0; k < MBOX * DEPTH / 2 / 64; ++k) dst[(k << 6) + lane] = src[(k << 6) + lane];
  }
  // ---- register state ----
  u64 rowlive = ~0ull;          // bit k of lane l = row (k<<6)+l live
  rl_lds[lane] = rowlive;
  u64 cb[4];                    // colbest (global key) for col (q<<6)+lane
  u64 la[4];                    // lookahead: next raw list entry (0 = exhausted)
  u64 cfc[4];                   // col-field constants: MBOX - j
  u32 posreg = 0x02020202u;     // 4x 8-bit next-list-index (after la)
  #pragma unroll
  for (int q = 0; q < 4; ++q) {
    int j = (q << 6) + lane;
    cfc[q] = (u64)(MBOX - j);
    u64 e0 = top[j * DEPTH];     // nonzero by construction
    u64 e1 = top[j * DEPTH + 1];
    cb[q] = ((e0 >> 13) << 22) | ((e0 & 0x1FFFull) << 9) | cfc[q];
    la[q] = e1;
  }

  // ---- 256 greedy steps, zero barriers, DPP argmax, deferred loss ----
  for (int step = 0; step < MBOX; ++step) {
    // argmax over 256 colbests: 2-level reg max + VALU DPP reduce (uniform out)
    u64 m0 = cb[0] > cb[1] ? cb[0] : cb[1];
    u64 m1 = cb[2] > cb[3] ? cb[2] : cb[3];
    u64 m = wave_max_u64(m0 > m1 ? m0 : m1);
    if (lane == 0) match[step] = (u32)m & 0x3FFFFFu;  // defer loss to tail
    if (step == MBOX - 1) break;
    const u32 rfield = (u32)(m >> 9) & 0x1FFFu;  // 4096 - i  (>= 1)
    const u32 cfield = (u32)m & 0x1FFu;          // 256 - jm
    const int i = NBOX - (int)rfield;
    // row i dies: owner lane updates reg + LDS mirror (same-wave DS order)
    if (lane == (i & 63)) {
      rowlive &= ~(1ull << (i >> 6));
      rl_lds[lane] = rowlive;
    }
    // slot updates: lookahead-first walk
    u32 exmask = 0;
    #pragma unroll
    for (int q = 0; q < 4; ++q) {
      const int j = (q << 6) + lane;
      u64 c = cb[q];
      if (cfield == (u32)cfc[q]) {
        cb[q] = 0ull;  // matched col retires
      } else if (((u32)(c >> 9) & 0x1FFFu) == rfield) {  // c==0 -> rowfield 0 != rfield
        int p = (int)((posreg >> (q * 8)) & 0xFFu);
        u64 e = la[q];  // pre-loaded candidate: one dependent rl read on the chain
        for (;;) {
          if (e == 0ull) break;  // exhausted (or zero-pad)
          int r = NBOX - (int)(e & 0x1FFFull);
          if ((rl_lds[r & 63] >> (r >> 6)) & 1ull) break;  // live
          e = (p < DEPTH) ? top[j * DEPTH + p] : 0ull;
          ++p;
        }
        if (e != 0ull) {
          cb[q] = ((e >> 13) << 22) | ((e & 0x1FFFull) << 9) | cfc[q];
          la[q] = (p < DEPTH) ? top[j * DEPTH + p] : 0ull;  // refill: latency hides
          ++p;
          posreg = (posreg & ~(0xFFu << (q * 8))) | ((u32)p << (q * 8));
        } else {
          cb[q] = 0ull;
          exmask |= (1u << q);
        }
      }
    }
    // rare inline rebuilds (wave-uniform loop; all lanes active inside)
    u64 exb = __ballot(exmask != 0);
    while (exb != 0ull) {
      const int src = (int)__ffsll((unsigned long long)exb) - 1;
      const u32 em = (u32)__shfl((int)exmask, src, 64);
      const int q = __ffs(em) - 1;
      const int jj = (q << 6) + src;
      if (lane == src) exmask &= ~(1u << q);
      exb = __ballot(exmask != 0);
      float4 gb = g[jj];
      float gar = garea[jj];
      u64 t[RDEPTH];
      #pragma unroll
      for (int z = 0; z < RDEPTH; ++z) t[z] = 0ull;
      for (int k = 0; k < 64; ++k) {
        if ((rowlive >> k) & 1ull) {  // own-lane liveness (transposed layout)
          int rr = (k << 6) + lane;
          float4 a = prs[rr];
          float areaA = (a.z - a.x) * (a.w - a.y);
          u64 key = ((u64)iou_bits(a, areaA, gb, gar) << 13) | (u64)(NBOX - rr);
          if (key > t[RDEPTH - 1]) {
            t[RDEPTH - 1] = key;
            #pragma unroll
            for (int z = RDEPTH - 1; z > 0; --z)
              if (t[z] > t[z - 1]) { u64 tmp = t[z]; t[z] = t[z - 1]; t[z - 1] = tmp; }
          }
        }
      }
      u64 ent0 = 0ull, ent1 = 0ull;
      int h = 0;
      for (int e = 0; e < RDEPTH; ++e) {
        u64 cand = 0;
        #pragma unroll
        for (int z = 0; z < RDEPTH; ++z) if (z == h) cand = t[z];
        u64 mm = wave_max_u64(cand);
        if (cand == mm && mm) h++;
        if (e == 0) ent0 = mm;
        if (e == 1) ent1 = mm;
        if (lane == 0) top[jj * DEPTH + e] = mm;
      }
      if (lane >= RDEPTH && lane < DEPTH) top[jj * DEPTH + lane] = 0ull;  // zero-pad
      if (lane == src) {
        cb[q] = ((ent0 >> 13) << 22) | ((ent0 & 0x1FFFull) << 9) | cfc[q];
        la[q] = ent1;  // >=3840 live rows -> ent0/ent1 nonzero, live
        posreg = (posreg & ~(0xFFu << (q * 8))) | (2u << (q * 8));
      }
    }
  }

  // ---- deferred loss: 4 matched pairs per lane (same order as rotating scheme) ----
  #pragma unroll
  for (int t4 = 0; t4 < 4; ++t4) {
    int s = (t4 << 6) + lane;
    u32 mm = match[s];
    int i = NBOX - (int)(mm >> 9);
    int j = MBOX - (int)(mm & 0x1FFu);
    float4 a = prs[i];
    float4 gg = g[j];
    possum += giou_loss(a.x, a.y, a.z, a.w, gg.x, gg.y, gg.z, gg.w);
    negsub += giou_loss(a.x, a.y, a.z, a.w, 0.0f, 0.0f, 0.0f, 0.0f);
  }

  // ---- final wave reduce: possum/256 + (negdiff - negsub)/3840 ----
  #pragma unroll
  for (int o = 32; o; o >>= 1) {
    possum  += __shfl_xor(possum, o, 64);
    negsub  += __shfl_xor(negsub, o, 64);
    negdiff += __shfl_xor(negdiff, o, 64);
  }
  if (lane == 0)
    partial[b] = possum / 256.0f + (negdiff - negsub) / 3840.0f;
}

__global__ void finalize_kernel(const float* __restrict__ partial, float* __restrict__ out) {
  if (threadIdx.x == 0) {
    float s = 0.0f;
    for (int i = 0; i < NBATCH; ++i) s += partial[i];
    out[0] = s / 64.0f;  // /count(=32)/2
  }
}

extern "C" void kernel_launch(void* const* d_in, const int* in_sizes, int n_in,
                              void* d_out, int out_size, void* d_ws, size_t ws_size,
                              hipStream_t stream) {
  (void)in_sizes; (void)n_in; (void)out_size; (void)ws_size;
  const float4* pr = (const float4*)d_in[0];
  const float4* gt = (const float4*)d_in[1];
  char* ws = (char*)d_ws;
  u64* topG = (u64*)ws;                                    // 32*256*12*8 = 768 KB
  float* partial = (float*)(ws + (size_t)NBATCH * MBOX * DEPTH * 8);
  float* out = (float*)d_out;

  // allow >64KB dynamic LDS (idempotent host-side attribute; not a stream op)
  hipFuncSetAttribute((const void*)greedy_kernel,
                      hipFuncAttributeMaxDynamicSharedMemorySize, LDS_BYTES);

  hipLaunchKernelGGL(init_cols, dim3(NBATCH * 64), dim3(256), 0, stream, pr, gt, topG);
  hipLaunchKernelGGL(greedy_kernel, dim3(NBATCH), dim3(64), LDS_BYTES, stream,
                     pr, gt, topG, partial);
  hipLaunchKernelGGL(finalize_kernel, dim3(1), dim3(64), 0, stream, partial, out);
}